// Round 7
// baseline (258.211 us; speedup 1.0000x reference)
//
#include <hip/hip_runtime.h>
#include <stdint.h>

#define B_ 2
#define S_ 2048
#define DM_ 2048
#define H_ 32
#define KVH_ 8
#define HD_ 64
#define NQK_ 3072   // 2048 q + 512 k + 512 v
#define GK 2048     // GEMM K (both big GEMMs)
#define NT 32       // GK / 64

typedef unsigned short u16;
typedef unsigned int u32;
typedef __attribute__((ext_vector_type(8))) short bf16x8;
typedef __attribute__((ext_vector_type(4))) float f32x4;

static __device__ __forceinline__ u16 f2bf(float f) {
  unsigned int u = __float_as_uint(f);
  u = (u + 0x7fffu + ((u >> 16) & 1u)) >> 16;
  return (u16)u;
}
static __device__ __forceinline__ float bf2f(u16 v) {
  unsigned int u = ((unsigned int)v) << 16;
  return __uint_as_float(u);
}

// global -> LDS direct (width 16). LDS dest = wave-uniform base + lane*16.
static __device__ __forceinline__ void gload16(const void* g, void* lds_wave_base) {
  __builtin_amdgcn_global_load_lds(
      (__attribute__((address_space(1))) unsigned int*)(uintptr_t)g,
      (__attribute__((address_space(3))) unsigned int*)(uintptr_t)lds_wave_base,
      16, 0, 0);
}

// ---------------- fp32 -> bf16 convert ----------------
__global__ void cvt_bf16(const float* __restrict__ in, u16* __restrict__ out, int n4) {
  int i = blockIdx.x * blockDim.x + threadIdx.x;
  if (i >= n4) return;
  const float4 v = ((const float4*)in)[i];
  ushort4 o;
  o.x = f2bf(v.x); o.y = f2bf(v.y); o.z = f2bf(v.z); o.w = f2bf(v.w);
  ((ushort4*)out)[i] = o;
}

// ======== 8-phase-class pipelined GEMM: C(MxN) = A(MxK) * B(NxK)^T =========
// BM=128, BN=256, BK=64; 512 threads (8 waves, 2M x 4N; per-wave 64x64).
// 3 LDS buffers (48KB each), counted vmcnt(8) once per K-tile, 2 barriers
// per phase, XOR-swizzled LDS (pre-swizzled global source), T5 setprio,
// T1 bijective XCD swizzle. K compile-time = GK (NT tiles of 64).
#define LOADFRAG(BUF, MH, NH)                                                   \
  do {                                                                          \
    const char* bufA = lds + (BUF) * 49152;                                     \
    const char* bufB = bufA + 16384;                                            \
    _Pragma("unroll") for (int i = 0; i < 2; i++)                               \
    _Pragma("unroll") for (int kk = 0; kk < 2; kk++) {                          \
      const int ra = wr + (2 * (MH) + i) * 16 + q;                              \
      af[i][kk] = *(const bf16x8*)(bufA + ra * 128 +                            \
                   ((kk * 64 + g * 16) ^ ((ra & 7) << 4)));                     \
      const int rb = wc + (2 * (NH) + i) * 16 + q;                              \
      bfv[i][kk] = *(const bf16x8*)(bufB + rb * 128 +                           \
                   ((kk * 64 + g * 16) ^ ((rb & 7) << 4)));                     \
    }                                                                           \
  } while (0)

#define MFMAQ(MH, NH)                                                           \
  do {                                                                          \
    __builtin_amdgcn_s_setprio(1);                                              \
    _Pragma("unroll") for (int i = 0; i < 2; i++)                               \
    _Pragma("unroll") for (int j = 0; j < 2; j++)                               \
    _Pragma("unroll") for (int kk = 0; kk < 2; kk++)                            \
      acc[2 * (MH) + i][2 * (NH) + j] = __builtin_amdgcn_mfma_f32_16x16x32_bf16(\
          af[i][kk], bfv[j][kk], acc[2 * (MH) + i][2 * (NH) + j], 0, 0, 0);     \
    __builtin_amdgcn_s_setprio(0);                                              \
  } while (0)

#define GBAR() asm volatile("s_barrier" ::: "memory")

template <bool BF16OUT>
__global__ __launch_bounds__(512, 2) void gemm8(const u16* __restrict__ A,
                                                const u16* __restrict__ Bw,
                                                void* __restrict__ Cv,
                                                int M, int N) {
  __shared__ char lds[3 * 49152];  // 144 KB
  const int t = threadIdx.x, lane = t & 63, w = t >> 6;
  const int q = lane & 15, g = lane >> 4;

  // T1: bijective XCD swizzle (gridDim.x % 8 == 0 for both shapes)
  const int cpx = gridDim.x >> 3;
  const int wg = (blockIdx.x & 7) * cpx + (blockIdx.x >> 3);
  const int nbx = N >> 8;
  const int bx = wg % nbx, by = wg / nbx;
  const int m0 = by * 128, n0 = bx * 256;
  const int wr = (w >> 2) * 64, wc = (w & 3) * 64;

  const char* Ab = (const char*)A;
  const char* Bb = (const char*)Bw;
  const size_t K2 = (size_t)GK * 2;

  f32x4 acc[4][4] = {};

  // staging: 16KB chunk = 2 gload16/thread; pre-swizzled global column
  const int P0 = t * 16, P1 = 8192 + t * 16;
  const int r0s = P0 >> 7, c0s = (P0 & 127) ^ ((r0s & 7) << 4);
  const int r1s = P1 >> 7, c1s = (P1 & 127) ^ ((r1s & 7) << 4);

  auto stA = [&](int buf, int kt) {
    char* d = lds + buf * 49152;
    gload16(Ab + (size_t)(m0 + r0s) * K2 + kt * 128 + c0s, d + (w << 10));
    gload16(Ab + (size_t)(m0 + r1s) * K2 + kt * 128 + c1s, d + 8192 + (w << 10));
  };
  auto stB = [&](int buf, int half, int kt) {
    char* d = lds + buf * 49152 + 16384 + half * 16384;
    gload16(Bb + (size_t)(n0 + half * 128 + r0s) * K2 + kt * 128 + c0s, d + (w << 10));
    gload16(Bb + (size_t)(n0 + half * 128 + r1s) * K2 + kt * 128 + c1s, d + 8192 + (w << 10));
  };

  // prologue: tiles 0 and 1 fully staged (12 loads in flight)
  stA(0, 0); stB(0, 0, 0); stB(0, 1, 0);
  stA(1, 1); stB(1, 0, 1); stB(1, 1, 1);

  for (int kt = 0; kt < NT; kt++) {
    const int cb_ = kt % 3;
    const int nb = (kt + 2) % 3;
    const bool pf = (kt + 2 < NT);
    bf16x8 af[2][2], bfv[2][2];

    // -- phase 0 (quadrant m-half 0, n-half 0): stage A(t+2), counted wait --
    if (pf) stA(nb, kt + 2);
    if (kt < NT - 2) {
      asm volatile("s_waitcnt vmcnt(8)" ::: "memory");   // retires all of tile kt
    } else if (kt == NT - 2) {
      asm volatile("s_waitcnt vmcnt(6)" ::: "memory");
    } else {
      asm volatile("s_waitcnt vmcnt(0)" ::: "memory");
    }
    GBAR();                      // all waves' tile-kt loads visible
    LOADFRAG(cb_, 0, 0);         // (after barrier: first reads of this tile)
    MFMAQ(0, 0);
    GBAR();

    // -- phase 1 (m-half 1, n-half 0): stage B0(t+2) --
    LOADFRAG(cb_, 1, 0);
    if (pf) stB(nb, 0, kt + 2);
    GBAR();
    MFMAQ(1, 0);
    GBAR();

    // -- phase 2 (m-half 0, n-half 1): stage B1(t+2) --
    LOADFRAG(cb_, 0, 1);
    if (pf) stB(nb, 1, kt + 2);
    GBAR();
    MFMAQ(0, 1);
    GBAR();

    // -- phase 3 (m-half 1, n-half 1) --
    LOADFRAG(cb_, 1, 1);
    GBAR();
    MFMAQ(1, 1);
    GBAR();
  }

  // epilogue: C write (no LDS use)
#pragma unroll
  for (int m = 0; m < 4; m++) {
    const int r0 = m0 + wr + m * 16 + g * 4;
#pragma unroll
    for (int n = 0; n < 4; n++) {
      const int c = n0 + wc + n * 16 + q;
#pragma unroll
      for (int j = 0; j < 4; j++) {
        if constexpr (BF16OUT)
          ((u16*)Cv)[(size_t)(r0 + j) * N + c] = f2bf(acc[m][n][j]);
        else
          ((float*)Cv)[(size_t)(r0 + j) * N + c] = acc[m][n][j];
      }
    }
  }
}

// ------- fused RMSNorm + RoPE, in-place on bf16 QKV buffer ------------------
__global__ void norm_rope_inplace(u16* __restrict__ QKV, const float* __restrict__ cosT,
                                  const float* __restrict__ sinT,
                                  const float* __restrict__ qw,
                                  const float* __restrict__ kw, float qscale) {
  const int r = blockIdx.x * 4 + (threadIdx.x >> 6);
  const int lane = threadIdx.x & 63;
  const int hh2 = r % 40;
  const int bs = r / 40;
  const int s = bs & (S_ - 1);
  const bool isq = hh2 < 32;
  u16* p = QKV + (size_t)bs * NQK_ + hh2 * 64 + lane;
  float x = bf2f(*p);
  float ss = x * x;
#pragma unroll
  for (int m = 1; m < 64; m <<= 1) ss += __shfl_xor(ss, m, 64);
  const float wgt = isq ? qw[lane] : kw[lane];
  float xn = x * rsqrtf(ss * (1.0f / 64.0f) + 1e-6f) * wgt;
  float pr = __shfl_xor(xn, 32, 64);
  float o = xn * cosT[s * 64 + lane] + (lane < 32 ? -pr : pr) * sinT[s * 64 + lane];
  *p = f2bf(o * (isq ? qscale : 1.0f));
}

// -------- V: bf16 QKV v-part (b,s,kvh,d) -> bf16 (b,kvh,d,s) ---------------
__global__ void v_transpose(const u16* __restrict__ QKV, u16* __restrict__ Vt) {
  __shared__ u16 tile[64][72];
  const int s0 = blockIdx.x * 64;
  const int bk = blockIdx.y;
  const int b = bk / KVH_, kvh = bk % KVH_;
  const int t = threadIdx.x;
#pragma unroll
  for (int it = 0; it < 16; it++) {
    int idx = it * 256 + t;
    int sl = idx >> 6, d = idx & 63;
    tile[sl][d] = QKV[(size_t)(b * S_ + s0 + sl) * NQK_ + 2560 + kvh * 64 + d];
  }
  __syncthreads();
#pragma unroll
  for (int it = 0; it < 16; it++) {
    int idx = it * 256 + t;
    int d = idx >> 6, sl = idx & 63;
    Vt[(((size_t)(b * KVH_ + kvh)) * HD_ + d) * S_ + s0 + sl] = tile[sl][d];
  }
}

// ---------------- flash attention (R4 structure, best measured) -------------
__global__ __launch_bounds__(256, 4) void attn_fwd(const u16* __restrict__ QKV,
                                                   const u16* __restrict__ Vt,
                                                   u16* __restrict__ Out) {
  __shared__ u16 Ksm[2][64 * 64];   // [key][d], XOR-swizzled 128B rows
  __shared__ u16 Vsm[2][64 * 64];   // [d][key], XOR-swizzled 128B rows
  __shared__ u16 Psm[4][16 * 64];   // per-wave P tile [q][kk], swizzled

  const int t = threadIdx.x, lane = t & 63, w = t >> 6;
  const int q = lane & 15, g = lane >> 4;

  const int fid = blockIdx.y * 16 + blockIdx.x;   // 0..1023
  const int xcd = fid & 7, slot = fid >> 3;       // slot 0..127
  const int kg = xcd * 2 + (slot >> 6);           // (b,kvh) group 0..15
  const int sub = slot & 63;
  const int ip = sub >> 2;                        // q-tile pair index 0..15
  const int b = kg >> 3, kvh = kg & 7;
  const int h = kvh * 4 + (sub & 3);

  const char* Kb = (const char*)(QKV + (size_t)b * S_ * NQK_ + 2048 + kvh * 64);
  const char* Vb = (const char*)(Vt + ((size_t)(b * KVH_ + kvh)) * HD_ * S_);

  const int SP0 = t * 16, SP1 = 4096 + t * 16;
  const int srow0 = SP0 >> 7, scb0 = (SP0 ^ ((srow0 & 7) << 4)) & 127;
  const int srow1 = SP1 >> 7, scb1 = (SP1 ^ ((srow1 & 7) << 4)) & 127;
  const int SB0 = (w << 10), SB1 = 4096 + (w << 10);
  const size_t KROW = (size_t)NQK_ * 2;

  auto STAGE = [&](int buf, int kt) {
    gload16(Kb + (size_t)(kt * 64 + srow0) * KROW + scb0, (char*)Ksm[buf] + SB0);
    gload16(Kb + (size_t)(kt * 64 + srow1) * KROW + scb1, (char*)Ksm[buf] + SB1);
    gload16(Vb + (size_t)srow0 * (S_ * 2) + (size_t)kt * 128 + scb0, (char*)Vsm[buf] + SB0);
    gload16(Vb + (size_t)srow1 * (S_ * 2) + (size_t)kt * 128 + scb1, (char*)Vsm[buf] + SB1);
  };

  const int swz = (q & 7) << 4;
  int koff[4][2], voff[4][2], pwoff[4][2], proff[2];
#pragma unroll
  for (int nt = 0; nt < 4; nt++)
#pragma unroll
    for (int hh = 0; hh < 2; hh++) {
      koff[nt][hh] = ((nt * 16 + q) * 128 + hh * 64 + g * 16) ^ swz;
      voff[nt][hh] = ((nt * 16 + q) * 128 + hh * 64 + g * 16) ^ swz;
      pwoff[nt][hh] = (q * 128 + nt * 32 + g * 8 + hh * 4) ^ swz;
    }
#pragma unroll
  for (int c = 0; c < 2; c++) proff[c] = (q * 128 + c * 64 + g * 16) ^ swz;

  bf16x8 ones;
#pragma unroll
  for (int j = 0; j < 8; j++) ones[j] = (short)0x3F80;

  auto process = [&](int qt) {
    const int q0w = qt * 64 + w * 16;
    bf16x8 aq[2];
    {
      const u16* qp = QKV + (size_t)(b * S_ + q0w + q) * NQK_ + h * 64 + g * 8;
      aq[0] = *(const bf16x8*)qp;
      aq[1] = *(const bf16x8*)(qp + 32);
    }
    f32x4 o_acc[4] = {};
    f32x4 l_acc = {};
    float m_i = -1e30f;

    STAGE(0, 0);
    __syncthreads();
    int cur = 0;

    for (int kt = 0; kt <= qt; kt++) {
      if (kt < qt) STAGE(cur ^ 1, kt + 1);

      f32x4 sc[4];
      __builtin_amdgcn_s_setprio(1);
#pragma unroll
      for (int nt = 0; nt < 4; nt++) {
        f32x4 s = {};
#pragma unroll
        for (int hh = 0; hh < 2; hh++) {
          bf16x8 bk = *(const bf16x8*)((const char*)Ksm[cur] + koff[nt][hh]);
          s = __builtin_amdgcn_mfma_f32_16x16x32_bf16(bk, aq[hh], s, 0, 0, 0);
        }
        sc[nt] = s;
      }
      __builtin_amdgcn_s_setprio(0);

      if (kt == qt) {
#pragma unroll
        for (int nt = 0; nt < 4; nt++)
#pragma unroll
          for (int r = 0; r < 4; r++)
            if (nt * 16 + g * 4 + r > w * 16 + q) sc[nt][r] = -1e30f;
      }

      float mx;
      {
        float m0 = fmaxf(fmaxf(sc[0][0], sc[0][1]), fmaxf(sc[0][2], sc[0][3]));
        float m1 = fmaxf(fmaxf(sc[1][0], sc[1][1]), fmaxf(sc[1][2], sc[1][3]));
        float m2 = fmaxf(fmaxf(sc[2][0], sc[2][1]), fmaxf(sc[2][2], sc[2][3]));
        float m3 = fmaxf(fmaxf(sc[3][0], sc[3][1]), fmaxf(sc[3][2], sc[3][3]));
        mx = fmaxf(fmaxf(m0, m1), fmaxf(m2, m3));
      }
      mx = fmaxf(mx, __shfl_xor(mx, 16, 64));
      mx = fmaxf(mx, __shfl_xor(mx, 32, 64));

      if (!__all(mx <= m_i + 8.0f)) {
        const float mn = fmaxf(m_i, mx);
        const float a = exp2f(m_i - mn);
        m_i = mn;
        float aT[4];
#pragma unroll
        for (int r = 0; r < 4; r++)
          aT[r] = __shfl(a, (lane & 48) + ((lane & 48) >> 2) + r, 64);
#pragma unroll
        for (int r = 0; r < 4; r++) {
          l_acc[r] *= aT[r];
#pragma unroll
          for (int dt = 0; dt < 4; dt++) o_acc[dt][r] *= aT[r];
        }
      }

#pragma unroll
      for (int nt = 0; nt < 4; nt++)
#pragma unroll
        for (int r = 0; r < 4; r++) sc[nt][r] = exp2f(sc[nt][r] - m_i);
#pragma unroll
      for (int nt = 0; nt < 4; nt++)
#pragma unroll
        for (int hh = 0; hh < 2; hh++) {
          u32 wv;
          asm("v_cvt_pk_bf16_f32 %0, %1, %2"
              : "=v"(wv) : "v"(sc[nt][2 * hh]), "v"(sc[nt][2 * hh + 1]));
          *(u32*)((char*)Psm[w] + pwoff[nt][hh]) = wv;
        }

      asm volatile("s_waitcnt lgkmcnt(0)" ::: "memory");
      __builtin_amdgcn_sched_barrier(0);

      bf16x8 pa[2];
#pragma unroll
      for (int c = 0; c < 2; c++)
        pa[c] = *(const bf16x8*)((const char*)Psm[w] + proff[c]);

      __builtin_amdgcn_s_setprio(1);
      l_acc = __builtin_amdgcn_mfma_f32_16x16x32_bf16(pa[0], ones, l_acc, 0, 0, 0);
      l_acc = __builtin_amdgcn_mfma_f32_16x16x32_bf16(pa[1], ones, l_acc, 0, 0, 0);
#pragma unroll
      for (int c = 0; c < 2; c++)
#pragma unroll
        for (int dt = 0; dt < 4; dt++) {
          bf16x8 bv = *(const bf16x8*)((const char*)Vsm[cur] + voff[dt][c]);
          o_acc[dt] = __builtin_amdgcn_mfma_f32_16x16x32_bf16(pa[c], bv, o_acc[dt], 0, 0, 0);
        }
      __builtin_amdgcn_s_setprio(0);

      __syncthreads();
      cur ^= 1;
    }

#pragma unroll
    for (int r = 0; r < 4; r++) {
      const int qg = q0w + g * 4 + r;
      const float inv = 1.0f / l_acc[r];
#pragma unroll
      for (int dt = 0; dt < 4; dt++)
        Out[(((size_t)b * S_ + qg) * H_ + h) * HD_ + dt * 16 + q] =
            f2bf(o_acc[dt][r] * inv);
    }
  };

  process(ip);
  process(31 - ip);
}

// ---------------- host launch ----------------
extern "C" void kernel_launch(void* const* d_in, const int* in_sizes, int n_in,
                              void* d_out, int out_size, void* d_ws, size_t ws_size,
                              hipStream_t stream) {
  const float* x  = (const float*)d_in[0];
  const float* rc = (const float*)d_in[1];
  const float* rs = (const float*)d_in[2];
  const float* Wq = (const float*)d_in[3];
  const float* Wk = (const float*)d_in[4];
  const float* Wv = (const float*)d_in[5];
  const float* Wo = (const float*)d_in[6];
  const float* qw = (const float*)d_in[7];
  const float* kw = (const float*)d_in[8];
  float* out = (float*)d_out;

  char* ws = (char*)d_ws;
  const size_t MB = (size_t)1 << 20;
  u16* xb   = (u16*)(ws + 0 * MB);    // 16 MB bf16 x (reused as attn-out)
  u16* wbq  = (u16*)(ws + 16 * MB);   // 12 MB bf16 [Wq;Wk;Wv] (then Wo reuse)
  u16* QKVb = (u16*)(ws + 28 * MB);   // 24 MB bf16 QKV proj (b,s,3072)
  u16* Vtb  = (u16*)(ws + 52 * MB);   // 4 MB  bf16 V (b,kvh,d,s)
  u16* AO   = xb;

  const int MT = B_ * S_;
  const float QSC = 0.125f * 1.44269504089f;  // (1/sqrt(64)) * log2(e)

  cvt_bf16<<<dim3(MT * DM_ / 1024), 256, 0, stream>>>(x, xb, MT * DM_ / 4);
  cvt_bf16<<<dim3(DM_ * DM_ / 1024), 256, 0, stream>>>(Wq, wbq, DM_ * DM_ / 4);
  cvt_bf16<<<dim3(512 * DM_ / 1024), 256, 0, stream>>>(Wk, wbq + (size_t)DM_ * DM_, 512 * DM_ / 4);
  cvt_bf16<<<dim3(512 * DM_ / 1024), 256, 0, stream>>>(Wv, wbq + (size_t)DM_ * DM_ + (size_t)512 * DM_, 512 * DM_ / 4);

  // fused QKV projection, bf16 out: 384 blocks (M/128=32 x N/256=12)
  gemm8<true><<<dim3(384), 512, 0, stream>>>(xb, wbq, QKVb, MT, NQK_);

  norm_rope_inplace<<<dim3(MT * 40 / 4), 256, 0, stream>>>(QKVb, rc, rs, qw, kw, QSC);

  v_transpose<<<dim3(S_ / 64, B_ * KVH_), 256, 0, stream>>>(QKVb, Vtb);

  // attention (R4 structure: 1024 balanced blocks, q-tile pairing)
  attn_fwd<<<dim3(16, 64), 256, 0, stream>>>(QKVb, Vtb, AO);

  cvt_bf16<<<dim3(DM_ * DM_ / 1024), 256, 0, stream>>>(Wo, wbq, DM_ * DM_ / 4);
  // output projection, fp32 out: 256 blocks (32 x 8)
  gemm8<false><<<dim3(256), 512, 0, stream>>>(AO, wbq, out, MT, DM_);
}

// Round 8
// 216.407 us; speedup vs baseline: 1.1932x; 1.1932x over previous
//
#include <hip/hip_runtime.h>
#include <stdint.h>

#define B_ 2
#define S_ 2048
#define DM_ 2048
#define H_ 32
#define KVH_ 8
#define HD_ 64
#define NQK_ 3072   // 2048 q + 512 k + 512 v

typedef unsigned short u16;
typedef unsigned int u32;
typedef __attribute__((ext_vector_type(8))) short bf16x8;
typedef __attribute__((ext_vector_type(4))) float f32x4;

static __device__ __forceinline__ u16 f2bf(float f) {
  unsigned int u = __float_as_uint(f);
  u = (u + 0x7fffu + ((u >> 16) & 1u)) >> 16;
  return (u16)u;
}

// global -> LDS direct (width 16). LDS dest = wave-uniform base + lane*16.
static __device__ __forceinline__ void gload16(const void* g, void* lds_wave_base) {
  __builtin_amdgcn_global_load_lds(
      (__attribute__((address_space(1))) unsigned int*)(uintptr_t)g,
      (__attribute__((address_space(3))) unsigned int*)(uintptr_t)lds_wave_base,
      16, 0, 0);
}

// ---------------- fused fp32 -> bf16 convert (x, Wq, Wk, Wv, Wo) -----------
__global__ void cvt_all(const float* __restrict__ x, const float* __restrict__ wq,
                        const float* __restrict__ wk, const float* __restrict__ wv,
                        const float* __restrict__ wo,
                        u16* __restrict__ xb, u16* __restrict__ wbq,
                        u16* __restrict__ wbo) {
  const int NX = 2097152, NQ = 1048576, NKV = 262144;  // float4 counts
  const int TOT = NX + NQ + 2 * NKV + NQ;              // 4718592
  const int stride = gridDim.x * 256;
  for (int i = blockIdx.x * 256 + threadIdx.x; i < TOT; i += stride) {
    const float4* s; ushort4* d; int off;
    if (i < NX)                { s = (const float4*)x;  d = (ushort4*)xb;  off = i; }
    else if (i < NX + NQ)      { s = (const float4*)wq; d = (ushort4*)wbq; off = i - NX; }
    else if (i < NX + NQ + NKV){ s = (const float4*)wk; d = (ushort4*)(wbq + (size_t)DM_ * DM_); off = i - NX - NQ; }
    else if (i < NX + NQ + 2 * NKV) { s = (const float4*)wv; d = (ushort4*)(wbq + (size_t)DM_ * DM_ + (size_t)512 * DM_); off = i - NX - NQ - NKV; }
    else                       { s = (const float4*)wo; d = (ushort4*)wbo; off = i - NX - NQ - 2 * NKV; }
    const float4 v = s[off];
    ushort4 o;
    o.x = f2bf(v.x); o.y = f2bf(v.y); o.z = f2bf(v.z); o.w = f2bf(v.w);
    d[off] = o;
  }
}

// ---------------- GEMM: C(MxN) = A(MxK) * B(NxK)^T, bf16 in ----------------
// 2-phase double-buffered 128x128 (measured best structure).
#define BM 128
#define BN 128
#define BK 32

#define GEMM_MAIN                                                               \
  __shared__ u16 As[2][BM * BK];                                                \
  __shared__ u16 Bs[2][BN * BK];                                                \
  const int t = threadIdx.x;                                                    \
  const int lane = t & 63;                                                      \
  const int w = t >> 6;                                                         \
  const int q = lane & 15, g = lane >> 4;                                       \
  const int wr = (w >> 1) * 64, wc = (w & 1) * 64;                              \
  const int m0 = blockIdx.y * BM;                                               \
  const int n0 = blockIdx.x * BN;                                               \
  f32x4 acc[4][4] = {};                                                         \
  const char* Ab = (const char*)A;                                              \
  const char* Bb = (const char*)Bw;                                             \
  const size_t K2 = (size_t)K * 2;                                              \
  const int P0 = t * 16;                                                        \
  const int row0 = P0 >> 6, kb0 = P0 & 63;                                      \
  const int P1 = 4096 + t * 16;                                                 \
  const int row1 = P1 >> 6, kb1 = P1 & 63;                                      \
  const int Pb0 = (w << 10), Pb1 = 4096 + (w << 10);                            \
  auto STAGE = [&](int buf, int k0) {                                           \
    gload16(Ab + (size_t)(m0 + row0) * K2 + (size_t)k0 * 2 + kb0, (char*)As[buf] + Pb0); \
    gload16(Ab + (size_t)(m0 + row1) * K2 + (size_t)k0 * 2 + kb1, (char*)As[buf] + Pb1); \
    gload16(Bb + (size_t)(n0 + row0) * K2 + (size_t)k0 * 2 + kb0, (char*)Bs[buf] + Pb0); \
    gload16(Bb + (size_t)(n0 + row1) * K2 + (size_t)k0 * 2 + kb1, (char*)Bs[buf] + Pb1); \
  };                                                                            \
  STAGE(0, 0);                                                                  \
  __syncthreads();                                                              \
  int cur = 0;                                                                  \
  for (int k0 = 0; k0 < K; k0 += BK) {                                          \
    if (k0 + BK < K) STAGE(cur ^ 1, k0 + BK);                                   \
    bf16x8 af[4], bfr[4];                                                       \
    _Pragma("unroll")                                                           \
    for (int m = 0; m < 4; m++)                                                 \
      af[m] = *(const bf16x8*)((const char*)As[cur] +                           \
               (wr + m * 16 + q) * 64 + (g << 4));                              \
    _Pragma("unroll")                                                           \
    for (int n = 0; n < 4; n++)                                                 \
      bfr[n] = *(const bf16x8*)((const char*)Bs[cur] +                          \
               (wc + n * 16 + q) * 64 + (g << 4));                              \
    _Pragma("unroll")                                                           \
    for (int m = 0; m < 4; m++)                                                 \
      _Pragma("unroll")                                                         \
      for (int n = 0; n < 4; n++)                                               \
        acc[m][n] = __builtin_amdgcn_mfma_f32_16x16x32_bf16(af[m], bfr[n], acc[m][n], 0, 0, 0); \
    __syncthreads();                                                            \
    cur ^= 1;                                                                   \
  }

// fp32-out GEMM (O-projection)
__global__ __launch_bounds__(256) void gemm_bt(const u16* __restrict__ A,
                                               const u16* __restrict__ Bw,
                                               float* __restrict__ C,
                                               int M, int N, int K) {
  GEMM_MAIN
#pragma unroll
  for (int m = 0; m < 4; m++) {
    const int r0 = m0 + wr + m * 16 + g * 4;
#pragma unroll
    for (int n = 0; n < 4; n++) {
      const int c = n0 + wc + n * 16 + q;
#pragma unroll
      for (int j = 0; j < 4; j++)
        C[(size_t)(r0 + j) * N + c] = acc[m][n][j];
    }
  }
}

// QKV GEMM with fused RMSNorm + RoPE epilogue (bf16 out).
// Each wave's 64 cols = exactly one head (hcol = (n0+wc)>>6: 0-31 Q,
// 32-39 K, 40-47 V). RMS: 4 lane-local squares + 4 shfl_xor over q-lanes.
// RoPE pairs d<->d+32 are lane-local (n <-> n+-2).
__global__ __launch_bounds__(256) void gemm_qkv(const u16* __restrict__ A,
                                                const u16* __restrict__ Bw,
                                                u16* __restrict__ C,
                                                const float* __restrict__ cosT,
                                                const float* __restrict__ sinT,
                                                const float* __restrict__ qwv,
                                                const float* __restrict__ kwv,
                                                float qscale,
                                                int M, int N, int K) {
  GEMM_MAIN
  const int hcol = (n0 + wc) >> 6;
  const bool isV = hcol >= 40;
  const bool isQ = hcol < 32;
  const float osc = isQ ? qscale : 1.0f;
  float wgt[4] = {1.f, 1.f, 1.f, 1.f};
  if (!isV) {
    const float* wp = isQ ? qwv : kwv;
#pragma unroll
    for (int n = 0; n < 4; n++) wgt[n] = wp[n * 16 + q];
  }
#pragma unroll
  for (int m = 0; m < 4; m++) {
#pragma unroll
    for (int j = 0; j < 4; j++) {
      const int row = m0 + wr + m * 16 + g * 4 + j;
      float v[4];
#pragma unroll
      for (int n = 0; n < 4; n++) v[n] = acc[m][n][j];
      if (!isV) {
        float ss = v[0] * v[0] + v[1] * v[1] + v[2] * v[2] + v[3] * v[3];
        ss += __shfl_xor(ss, 1, 64);
        ss += __shfl_xor(ss, 2, 64);
        ss += __shfl_xor(ss, 4, 64);
        ss += __shfl_xor(ss, 8, 64);
        const float inv = rsqrtf(ss * (1.0f / 64.0f) + 1e-6f);
        const int s = row & (S_ - 1);
        float xn[4];
#pragma unroll
        for (int n = 0; n < 4; n++) xn[n] = v[n] * inv * wgt[n];
#pragma unroll
        for (int n = 0; n < 4; n++) {
          const float rot = (n < 2) ? -xn[n + 2] : xn[n - 2];
          const int d = n * 16 + q;
          v[n] = (xn[n] * cosT[s * 64 + d] + rot * sinT[s * 64 + d]) * osc;
        }
      }
#pragma unroll
      for (int n = 0; n < 4; n++)
        C[(size_t)row * N + (n0 + wc + n * 16 + q)] = f2bf(v[n]);
    }
  }
}

// -------- V: bf16 QKV v-part (b,s,kvh,d) -> bf16 (b,kvh,d,s) ---------------
__global__ void v_transpose(const u16* __restrict__ QKV, u16* __restrict__ Vt) {
  __shared__ u16 tile[64][72];
  const int s0 = blockIdx.x * 64;
  const int bk = blockIdx.y;
  const int b = bk / KVH_, kvh = bk % KVH_;
  const int t = threadIdx.x;
#pragma unroll
  for (int it = 0; it < 16; it++) {
    int idx = it * 256 + t;
    int sl = idx >> 6, d = idx & 63;
    tile[sl][d] = QKV[(size_t)(b * S_ + s0 + sl) * NQK_ + 2560 + kvh * 64 + d];
  }
  __syncthreads();
#pragma unroll
  for (int it = 0; it < 16; it++) {
    int idx = it * 256 + t;
    int d = idx >> 6, sl = idx & 63;
    Vt[(((size_t)(b * KVH_ + kvh)) * HD_ + d) * S_ + s0 + sl] = tile[sl][d];
  }
}

// ---------------- flash attention (R4 structure, best measured) -------------
__global__ __launch_bounds__(256, 4) void attn_fwd(const u16* __restrict__ QKV,
                                                   const u16* __restrict__ Vt,
                                                   u16* __restrict__ Out) {
  __shared__ u16 Ksm[2][64 * 64];   // [key][d], XOR-swizzled 128B rows
  __shared__ u16 Vsm[2][64 * 64];   // [d][key], XOR-swizzled 128B rows
  __shared__ u16 Psm[4][16 * 64];   // per-wave P tile [q][kk], swizzled

  const int t = threadIdx.x, lane = t & 63, w = t >> 6;
  const int q = lane & 15, g = lane >> 4;

  const int fid = blockIdx.y * 16 + blockIdx.x;   // 0..1023
  const int xcd = fid & 7, slot = fid >> 3;       // slot 0..127
  const int kg = xcd * 2 + (slot >> 6);           // (b,kvh) group 0..15
  const int sub = slot & 63;
  const int ip = sub >> 2;                        // q-tile pair index 0..15
  const int b = kg >> 3, kvh = kg & 7;
  const int h = kvh * 4 + (sub & 3);

  const char* Kb = (const char*)(QKV + (size_t)b * S_ * NQK_ + 2048 + kvh * 64);
  const char* Vb = (const char*)(Vt + ((size_t)(b * KVH_ + kvh)) * HD_ * S_);

  const int SP0 = t * 16, SP1 = 4096 + t * 16;
  const int srow0 = SP0 >> 7, scb0 = (SP0 ^ ((srow0 & 7) << 4)) & 127;
  const int srow1 = SP1 >> 7, scb1 = (SP1 ^ ((srow1 & 7) << 4)) & 127;
  const int SB0 = (w << 10), SB1 = 4096 + (w << 10);
  const size_t KROW = (size_t)NQK_ * 2;

  auto STAGE = [&](int buf, int kt) {
    gload16(Kb + (size_t)(kt * 64 + srow0) * KROW + scb0, (char*)Ksm[buf] + SB0);
    gload16(Kb + (size_t)(kt * 64 + srow1) * KROW + scb1, (char*)Ksm[buf] + SB1);
    gload16(Vb + (size_t)srow0 * (S_ * 2) + (size_t)kt * 128 + scb0, (char*)Vsm[buf] + SB0);
    gload16(Vb + (size_t)srow1 * (S_ * 2) + (size_t)kt * 128 + scb1, (char*)Vsm[buf] + SB1);
  };

  const int swz = (q & 7) << 4;
  int koff[4][2], voff[4][2], pwoff[4][2], proff[2];
#pragma unroll
  for (int nt = 0; nt < 4; nt++)
#pragma unroll
    for (int hh = 0; hh < 2; hh++) {
      koff[nt][hh] = ((nt * 16 + q) * 128 + hh * 64 + g * 16) ^ swz;
      voff[nt][hh] = ((nt * 16 + q) * 128 + hh * 64 + g * 16) ^ swz;
      pwoff[nt][hh] = (q * 128 + nt * 32 + g * 8 + hh * 4) ^ swz;
    }
#pragma unroll
  for (int c = 0; c < 2; c++) proff[c] = (q * 128 + c * 64 + g * 16) ^ swz;

  bf16x8 ones;
#pragma unroll
  for (int j = 0; j < 8; j++) ones[j] = (short)0x3F80;

  auto process = [&](int qt) {
    const int q0w = qt * 64 + w * 16;
    bf16x8 aq[2];
    {
      const u16* qp = QKV + (size_t)(b * S_ + q0w + q) * NQK_ + h * 64 + g * 8;
      aq[0] = *(const bf16x8*)qp;
      aq[1] = *(const bf16x8*)(qp + 32);
    }
    f32x4 o_acc[4] = {};
    f32x4 l_acc = {};
    float m_i = -1e30f;

    STAGE(0, 0);
    __syncthreads();
    int cur = 0;

    for (int kt = 0; kt <= qt; kt++) {
      if (kt < qt) STAGE(cur ^ 1, kt + 1);

      f32x4 sc[4];
      __builtin_amdgcn_s_setprio(1);
#pragma unroll
      for (int nt = 0; nt < 4; nt++) {
        f32x4 s = {};
#pragma unroll
        for (int hh = 0; hh < 2; hh++) {
          bf16x8 bk = *(const bf16x8*)((const char*)Ksm[cur] + koff[nt][hh]);
          s = __builtin_amdgcn_mfma_f32_16x16x32_bf16(bk, aq[hh], s, 0, 0, 0);
        }
        sc[nt] = s;
      }
      __builtin_amdgcn_s_setprio(0);

      if (kt == qt) {
#pragma unroll
        for (int nt = 0; nt < 4; nt++)
#pragma unroll
          for (int r = 0; r < 4; r++)
            if (nt * 16 + g * 4 + r > w * 16 + q) sc[nt][r] = -1e30f;
      }

      float mx;
      {
        float m0 = fmaxf(fmaxf(sc[0][0], sc[0][1]), fmaxf(sc[0][2], sc[0][3]));
        float m1 = fmaxf(fmaxf(sc[1][0], sc[1][1]), fmaxf(sc[1][2], sc[1][3]));
        float m2 = fmaxf(fmaxf(sc[2][0], sc[2][1]), fmaxf(sc[2][2], sc[2][3]));
        float m3 = fmaxf(fmaxf(sc[3][0], sc[3][1]), fmaxf(sc[3][2], sc[3][3]));
        mx = fmaxf(fmaxf(m0, m1), fmaxf(m2, m3));
      }
      mx = fmaxf(mx, __shfl_xor(mx, 16, 64));
      mx = fmaxf(mx, __shfl_xor(mx, 32, 64));

      if (!__all(mx <= m_i + 8.0f)) {
        const float mn = fmaxf(m_i, mx);
        const float a = exp2f(m_i - mn);
        m_i = mn;
        float aT[4];
#pragma unroll
        for (int r = 0; r < 4; r++)
          aT[r] = __shfl(a, (lane & 48) + ((lane & 48) >> 2) + r, 64);
#pragma unroll
        for (int r = 0; r < 4; r++) {
          l_acc[r] *= aT[r];
#pragma unroll
          for (int dt = 0; dt < 4; dt++) o_acc[dt][r] *= aT[r];
        }
      }

#pragma unroll
      for (int nt = 0; nt < 4; nt++)
#pragma unroll
        for (int r = 0; r < 4; r++) sc[nt][r] = exp2f(sc[nt][r] - m_i);
#pragma unroll
      for (int nt = 0; nt < 4; nt++)
#pragma unroll
        for (int hh = 0; hh < 2; hh++) {
          u32 wv;
          asm("v_cvt_pk_bf16_f32 %0, %1, %2"
              : "=v"(wv) : "v"(sc[nt][2 * hh]), "v"(sc[nt][2 * hh + 1]));
          *(u32*)((char*)Psm[w] + pwoff[nt][hh]) = wv;
        }

      asm volatile("s_waitcnt lgkmcnt(0)" ::: "memory");
      __builtin_amdgcn_sched_barrier(0);

      bf16x8 pa[2];
#pragma unroll
      for (int c = 0; c < 2; c++)
        pa[c] = *(const bf16x8*)((const char*)Psm[w] + proff[c]);

      __builtin_amdgcn_s_setprio(1);
      l_acc = __builtin_amdgcn_mfma_f32_16x16x32_bf16(pa[0], ones, l_acc, 0, 0, 0);
      l_acc = __builtin_amdgcn_mfma_f32_16x16x32_bf16(pa[1], ones, l_acc, 0, 0, 0);
#pragma unroll
      for (int c = 0; c < 2; c++)
#pragma unroll
        for (int dt = 0; dt < 4; dt++) {
          bf16x8 bv = *(const bf16x8*)((const char*)Vsm[cur] + voff[dt][c]);
          o_acc[dt] = __builtin_amdgcn_mfma_f32_16x16x32_bf16(pa[c], bv, o_acc[dt], 0, 0, 0);
        }
      __builtin_amdgcn_s_setprio(0);

      __syncthreads();
      cur ^= 1;
    }

#pragma unroll
    for (int r = 0; r < 4; r++) {
      const int qg = q0w + g * 4 + r;
      const float inv = 1.0f / l_acc[r];
#pragma unroll
      for (int dt = 0; dt < 4; dt++)
        Out[(((size_t)b * S_ + qg) * H_ + h) * HD_ + dt * 16 + q] =
            f2bf(o_acc[dt][r] * inv);
    }
  };

  process(ip);
  process(31 - ip);
}

// ---------------- host launch ----------------
extern "C" void kernel_launch(void* const* d_in, const int* in_sizes, int n_in,
                              void* d_out, int out_size, void* d_ws, size_t ws_size,
                              hipStream_t stream) {
  const float* x  = (const float*)d_in[0];
  const float* rc = (const float*)d_in[1];
  const float* rs = (const float*)d_in[2];
  const float* Wq = (const float*)d_in[3];
  const float* Wk = (const float*)d_in[4];
  const float* Wv = (const float*)d_in[5];
  const float* Wo = (const float*)d_in[6];
  const float* qw = (const float*)d_in[7];
  const float* kw = (const float*)d_in[8];
  float* out = (float*)d_out;

  char* ws = (char*)d_ws;
  const size_t MB = (size_t)1 << 20;
  u16* xb   = (u16*)(ws + 0 * MB);    // 16 MB bf16 x (reused as attn-out)
  u16* wbq  = (u16*)(ws + 16 * MB);   // 12 MB bf16 [Wq;Wk;Wv]
  u16* wbo  = (u16*)(ws + 28 * MB);   // 8 MB  bf16 Wo
  u16* QKVb = (u16*)(ws + 36 * MB);   // 24 MB bf16 QKV proj (b,s,3072)
  u16* Vtb  = (u16*)(ws + 60 * MB);   // 4 MB  bf16 V (b,kvh,d,s) -> 64 MB
  u16* AO   = xb;

  const int MT = B_ * S_;
  const float QSC = 0.125f * 1.44269504089f;  // (1/sqrt(64)) * log2(e)

  // one fused convert pass: x, Wq, Wk, Wv, Wo -> bf16
  cvt_all<<<dim3(2048), 256, 0, stream>>>(x, Wq, Wk, Wv, Wo, xb, wbq, wbo);

  // QKV projection with fused RMSNorm+RoPE epilogue (Q scaled by log2e/8)
  gemm_qkv<<<dim3(NQK_ / BN, MT / BM), 256, 0, stream>>>(
      xb, wbq, QKVb, rc, rs, qw, kw, QSC, MT, NQK_, DM_);

  // V -> (b,kvh,d,s)
  v_transpose<<<dim3(S_ / 64, B_ * KVH_), 256, 0, stream>>>(QKVb, Vtb);

  // attention (R4 structure: 1024 balanced blocks, q-tile pairing)
  attn_fwd<<<dim3(16, 64), 256, 0, stream>>>(QKVb, Vtb, AO);

  // output projection -> d_out (fp32)
  gemm_bt<<<dim3(DM_ / BN, MT / BM), 256, 0, stream>>>(AO, wbo, out, MT, DM_, DM_);
}

// Round 10
// 206.712 us; speedup vs baseline: 1.2491x; 1.0469x over previous
//
#include <hip/hip_runtime.h>
#include <stdint.h>

#define B_ 2
#define S_ 2048
#define DM_ 2048
#define H_ 32
#define KVH_ 8
#define HD_ 64
#define NQK_ 3072   // 2048 q + 512 k + 512 v

typedef unsigned short u16;
typedef unsigned int u32;
typedef __attribute__((ext_vector_type(8))) short bf16x8;
typedef __attribute__((ext_vector_type(4))) float f32x4;

static __device__ __forceinline__ u16 f2bf(float f) {
  unsigned int u = __float_as_uint(f);
  u = (u + 0x7fffu + ((u >> 16) & 1u)) >> 16;
  return (u16)u;
}

// global -> LDS direct (width 16). LDS dest = wave-uniform base + lane*16.
static __device__ __forceinline__ void gload16(const void* g, void* lds_wave_base) {
  __builtin_amdgcn_global_load_lds(
      (__attribute__((address_space(1))) unsigned int*)(uintptr_t)g,
      (__attribute__((address_space(3))) unsigned int*)(uintptr_t)lds_wave_base,
      16, 0, 0);
}

// ---------------- fused fp32 -> bf16 convert (x, Wq, Wk, Wv, Wo) -----------
__global__ void cvt_all(const float* __restrict__ x, const float* __restrict__ wq,
                        const float* __restrict__ wk, const float* __restrict__ wv,
                        const float* __restrict__ wo,
                        u16* __restrict__ xb, u16* __restrict__ wbq,
                        u16* __restrict__ wbo) {
  const int NX = 2097152, NQ = 1048576, NKV = 262144;  // float4 counts
  const int TOT = NX + NQ + 2 * NKV + NQ;              // 4718592
  const int stride = gridDim.x * 256;
  for (int i = blockIdx.x * 256 + threadIdx.x; i < TOT; i += stride) {
    const float4* s; ushort4* d; int off;
    if (i < NX)                { s = (const float4*)x;  d = (ushort4*)xb;  off = i; }
    else if (i < NX + NQ)      { s = (const float4*)wq; d = (ushort4*)wbq; off = i - NX; }
    else if (i < NX + NQ + NKV){ s = (const float4*)wk; d = (ushort4*)(wbq + (size_t)DM_ * DM_); off = i - NX - NQ; }
    else if (i < NX + NQ + 2 * NKV) { s = (const float4*)wv; d = (ushort4*)(wbq + (size_t)DM_ * DM_ + (size_t)512 * DM_); off = i - NX - NQ - NKV; }
    else                       { s = (const float4*)wo; d = (ushort4*)wbo; off = i - NX - NQ - 2 * NKV; }
    const float4 v = s[off];
    ushort4 o;
    o.x = f2bf(v.x); o.y = f2bf(v.y); o.z = f2bf(v.z); o.w = f2bf(v.w);
    d[off] = o;
  }
}

// ---------------- GEMM: C(MxN) = A(MxK) * B(NxK)^T, bf16 in ----------------
// 2-phase double-buffered 128x128 (measured best structure).
#define BM 128
#define BN 128
#define BK 32

#define GEMM_MAIN                                                               \
  __shared__ u16 As[2][BM * BK];                                                \
  __shared__ u16 Bs[2][BN * BK];                                                \
  const int t = threadIdx.x;                                                    \
  const int lane = t & 63;                                                      \
  const int w = t >> 6;                                                         \
  const int q = lane & 15, g = lane >> 4;                                       \
  const int wr = (w >> 1) * 64, wc = (w & 1) * 64;                              \
  const int m0 = blockIdx.y * BM;                                               \
  const int n0 = blockIdx.x * BN;                                               \
  f32x4 acc[4][4] = {};                                                         \
  const char* Ab = (const char*)A;                                              \
  const char* Bb = (const char*)Bw;                                             \
  const size_t K2 = (size_t)K * 2;                                              \
  const int P0 = t * 16;                                                        \
  const int row0 = P0 >> 6, kb0 = P0 & 63;                                      \
  const int P1 = 4096 + t * 16;                                                 \
  const int row1 = P1 >> 6, kb1 = P1 & 63;                                      \
  const int Pb0 = (w << 10), Pb1 = 4096 + (w << 10);                            \
  auto STAGE = [&](int buf, int k0) {                                           \
    gload16(Ab + (size_t)(m0 + row0) * K2 + (size_t)k0 * 2 + kb0, (char*)As[buf] + Pb0); \
    gload16(Ab + (size_t)(m0 + row1) * K2 + (size_t)k0 * 2 + kb1, (char*)As[buf] + Pb1); \
    gload16(Bb + (size_t)(n0 + row0) * K2 + (size_t)k0 * 2 + kb0, (char*)Bs[buf] + Pb0); \
    gload16(Bb + (size_t)(n0 + row1) * K2 + (size_t)k0 * 2 + kb1, (char*)Bs[buf] + Pb1); \
  };                                                                            \
  STAGE(0, 0);                                                                  \
  __syncthreads();                                                              \
  int cur = 0;                                                                  \
  for (int k0 = 0; k0 < K; k0 += BK) {                                          \
    if (k0 + BK < K) STAGE(cur ^ 1, k0 + BK);                                   \
    bf16x8 af[4], bfr[4];                                                       \
    _Pragma("unroll")                                                           \
    for (int m = 0; m < 4; m++)                                                 \
      af[m] = *(const bf16x8*)((const char*)As[cur] +                           \
               (wr + m * 16 + q) * 64 + (g << 4));                              \
    _Pragma("unroll")                                                           \
    for (int n = 0; n < 4; n++)                                                 \
      bfr[n] = *(const bf16x8*)((const char*)Bs[cur] +                          \
               (wc + n * 16 + q) * 64 + (g << 4));                              \
    _Pragma("unroll")                                                           \
    for (int m = 0; m < 4; m++)                                                 \
      _Pragma("unroll")                                                         \
      for (int n = 0; n < 4; n++)                                               \
        acc[m][n] = __builtin_amdgcn_mfma_f32_16x16x32_bf16(af[m], bfr[n], acc[m][n], 0, 0, 0); \
    __syncthreads();                                                            \
    cur ^= 1;                                                                   \
  }

// fp32-out GEMM (O-projection)
__global__ __launch_bounds__(256) void gemm_bt(const u16* __restrict__ A,
                                               const u16* __restrict__ Bw,
                                               float* __restrict__ C,
                                               int M, int N, int K) {
  GEMM_MAIN
#pragma unroll
  for (int m = 0; m < 4; m++) {
    const int r0 = m0 + wr + m * 16 + g * 4;
#pragma unroll
    for (int n = 0; n < 4; n++) {
      const int c = n0 + wc + n * 16 + q;
#pragma unroll
      for (int j = 0; j < 4; j++)
        C[(size_t)(r0 + j) * N + c] = acc[m][n][j];
    }
  }
}

// QKV GEMM with fused RMSNorm + RoPE epilogue (bf16 out).
__global__ __launch_bounds__(256) void gemm_qkv(const u16* __restrict__ A,
                                                const u16* __restrict__ Bw,
                                                u16* __restrict__ C,
                                                const float* __restrict__ cosT,
                                                const float* __restrict__ sinT,
                                                const float* __restrict__ qwv,
                                                const float* __restrict__ kwv,
                                                float qscale,
                                                int M, int N, int K) {
  GEMM_MAIN
  const int hcol = (n0 + wc) >> 6;
  const bool isV = hcol >= 40;
  const bool isQ = hcol < 32;
  const float osc = isQ ? qscale : 1.0f;
  float wgt[4] = {1.f, 1.f, 1.f, 1.f};
  if (!isV) {
    const float* wp = isQ ? qwv : kwv;
#pragma unroll
    for (int n = 0; n < 4; n++) wgt[n] = wp[n * 16 + q];
  }
#pragma unroll
  for (int m = 0; m < 4; m++) {
#pragma unroll
    for (int j = 0; j < 4; j++) {
      const int row = m0 + wr + m * 16 + g * 4 + j;
      float v[4];
#pragma unroll
      for (int n = 0; n < 4; n++) v[n] = acc[m][n][j];
      if (!isV) {
        float ss = v[0] * v[0] + v[1] * v[1] + v[2] * v[2] + v[3] * v[3];
        ss += __shfl_xor(ss, 1, 64);
        ss += __shfl_xor(ss, 2, 64);
        ss += __shfl_xor(ss, 4, 64);
        ss += __shfl_xor(ss, 8, 64);
        const float inv = rsqrtf(ss * (1.0f / 64.0f) + 1e-6f);
        const int s = row & (S_ - 1);
        float xn[4];
#pragma unroll
        for (int n = 0; n < 4; n++) xn[n] = v[n] * inv * wgt[n];
#pragma unroll
        for (int n = 0; n < 4; n++) {
          const float rot = (n < 2) ? -xn[n + 2] : xn[n - 2];
          const int d = n * 16 + q;
          v[n] = (xn[n] * cosT[s * 64 + d] + rot * sinT[s * 64 + d]) * osc;
        }
      }
#pragma unroll
      for (int n = 0; n < 4; n++)
        C[(size_t)row * N + (n0 + wc + n * 16 + q)] = f2bf(v[n]);
    }
  }
}

// -------- V: bf16 QKV v-part (b,s,kvh,d) -> bf16 (b,kvh,d,s) ---------------
__global__ void v_transpose(const u16* __restrict__ QKV, u16* __restrict__ Vt) {
  __shared__ u16 tile[64][72];
  const int s0 = blockIdx.x * 64;
  const int bk = blockIdx.y;
  const int b = bk / KVH_, kvh = bk % KVH_;
  const int t = threadIdx.x;
#pragma unroll
  for (int it = 0; it < 16; it++) {
    int idx = it * 256 + t;
    int sl = idx >> 6, d = idx & 63;
    tile[sl][d] = QKV[(size_t)(b * S_ + s0 + sl) * NQK_ + 2560 + kvh * 64 + d];
  }
  __syncthreads();
#pragma unroll
  for (int it = 0; it < 16; it++) {
    int idx = it * 256 + t;
    int d = idx >> 6, sl = idx & 63;
    Vt[(((size_t)(b * KVH_ + kvh)) * HD_ + d) * S_ + s0 + sl] = tile[sl][d];
  }
}

// ---------------- flash attention (R8 structure + constant-shift softmax) ---
// Scores bounded (RMS-normed q,k): |s_log2| <= 11.6. P = exp2(s - 12) keeps
// P in (0,1] (same magnitude regime as adaptive-max R8) with no max tracking,
// no cross-lane reduce, no rescale. Softmax is shift-invariant; o/l cancels
// the 2^-12.
__global__ __launch_bounds__(256, 4) void attn_fwd(const u16* __restrict__ QKV,
                                                   const u16* __restrict__ Vt,
                                                   u16* __restrict__ Out) {
  __shared__ u16 Ksm[2][64 * 64];   // [key][d], XOR-swizzled 128B rows
  __shared__ u16 Vsm[2][64 * 64];   // [d][key], XOR-swizzled 128B rows
  __shared__ u16 Psm[4][16 * 64];   // per-wave P tile [q][kk], swizzled

  const int t = threadIdx.x, lane = t & 63, w = t >> 6;
  const int q = lane & 15, g = lane >> 4;

  const int fid = blockIdx.y * 16 + blockIdx.x;   // 0..1023
  const int xcd = fid & 7, slot = fid >> 3;       // slot 0..127
  const int kg = xcd * 2 + (slot >> 6);           // (b,kvh) group 0..15
  const int sub = slot & 63;
  const int ip = sub >> 2;                        // q-tile pair index 0..15
  const int b = kg >> 3, kvh = kg & 7;
  const int h = kvh * 4 + (sub & 3);

  const char* Kb = (const char*)(QKV + (size_t)b * S_ * NQK_ + 2048 + kvh * 64);
  const char* Vb = (const char*)(Vt + ((size_t)(b * KVH_ + kvh)) * HD_ * S_);

  const int SP0 = t * 16, SP1 = 4096 + t * 16;
  const int srow0 = SP0 >> 7, scb0 = (SP0 ^ ((srow0 & 7) << 4)) & 127;
  const int srow1 = SP1 >> 7, scb1 = (SP1 ^ ((srow1 & 7) << 4)) & 127;
  const int SB0 = (w << 10), SB1 = 4096 + (w << 10);
  const size_t KROW = (size_t)NQK_ * 2;

  auto STAGE = [&](int buf, int kt) {
    gload16(Kb + (size_t)(kt * 64 + srow0) * KROW + scb0, (char*)Ksm[buf] + SB0);
    gload16(Kb + (size_t)(kt * 64 + srow1) * KROW + scb1, (char*)Ksm[buf] + SB1);
    gload16(Vb + (size_t)srow0 * (S_ * 2) + (size_t)kt * 128 + scb0, (char*)Vsm[buf] + SB0);
    gload16(Vb + (size_t)srow1 * (S_ * 2) + (size_t)kt * 128 + scb1, (char*)Vsm[buf] + SB1);
  };

  const int swz = (q & 7) << 4;
  int koff[4][2], voff[4][2], pwoff[4][2], proff[2];
#pragma unroll
  for (int nt = 0; nt < 4; nt++)
#pragma unroll
    for (int hh = 0; hh < 2; hh++) {
      koff[nt][hh] = ((nt * 16 + q) * 128 + hh * 64 + g * 16) ^ swz;
      voff[nt][hh] = ((nt * 16 + q) * 128 + hh * 64 + g * 16) ^ swz;
      pwoff[nt][hh] = (q * 128 + nt * 32 + g * 8 + hh * 4) ^ swz;
    }
#pragma unroll
  for (int c = 0; c < 2; c++) proff[c] = (q * 128 + c * 64 + g * 16) ^ swz;

  bf16x8 ones;
#pragma unroll
  for (int j = 0; j < 8; j++) ones[j] = (short)0x3F80;

  auto process = [&](int qt) {
    const int q0w = qt * 64 + w * 16;
    bf16x8 aq[2];
    {
      const u16* qp = QKV + (size_t)(b * S_ + q0w + q) * NQK_ + h * 64 + g * 8;
      aq[0] = *(const bf16x8*)qp;
      aq[1] = *(const bf16x8*)(qp + 32);
    }
    f32x4 o_acc[4] = {};
    f32x4 l_acc = {};

    STAGE(0, 0);
    __syncthreads();
    int cur = 0;

    for (int kt = 0; kt <= qt; kt++) {
      if (kt < qt) STAGE(cur ^ 1, kt + 1);

      f32x4 sc[4];
      __builtin_amdgcn_s_setprio(1);
#pragma unroll
      for (int nt = 0; nt < 4; nt++) {
        f32x4 s = {};
#pragma unroll
        for (int hh = 0; hh < 2; hh++) {
          bf16x8 bk = *(const bf16x8*)((const char*)Ksm[cur] + koff[nt][hh]);
          s = __builtin_amdgcn_mfma_f32_16x16x32_bf16(bk, aq[hh], s, 0, 0, 0);
        }
        sc[nt] = s;
      }
      __builtin_amdgcn_s_setprio(0);

      if (kt == qt) {
#pragma unroll
        for (int nt = 0; nt < 4; nt++)
#pragma unroll
          for (int r = 0; r < 4; r++)
            if (nt * 16 + g * 4 + r > w * 16 + q) sc[nt][r] = -1e30f;
      }

      // constant-shift softmax: P = exp2(s - 12) in (0, 1]
#pragma unroll
      for (int nt = 0; nt < 4; nt++)
#pragma unroll
        for (int r = 0; r < 4; r++) sc[nt][r] = exp2f(sc[nt][r] - 12.0f);
#pragma unroll
      for (int nt = 0; nt < 4; nt++)
#pragma unroll
        for (int hh = 0; hh < 2; hh++) {
          u32 wv;
          asm("v_cvt_pk_bf16_f32 %0, %1, %2"
              : "=v"(wv) : "v"(sc[nt][2 * hh]), "v"(sc[nt][2 * hh + 1]));
          *(u32*)((char*)Psm[w] + pwoff[nt][hh]) = wv;
        }

      asm volatile("s_waitcnt lgkmcnt(0)" ::: "memory");
      __builtin_amdgcn_sched_barrier(0);

      bf16x8 pa[2];
#pragma unroll
      for (int c = 0; c < 2; c++)
        pa[c] = *(const bf16x8*)((const char*)Psm[w] + proff[c]);

      __builtin_amdgcn_s_setprio(1);
      l_acc = __builtin_amdgcn_mfma_f32_16x16x32_bf16(pa[0], ones, l_acc, 0, 0, 0);
      l_acc = __builtin_amdgcn_mfma_f32_16x16x32_bf16(pa[1], ones, l_acc, 0, 0, 0);
#pragma unroll
      for (int c = 0; c < 2; c++)
#pragma unroll
        for (int dt = 0; dt < 4; dt++) {
          bf16x8 bv = *(const bf16x8*)((const char*)Vsm[cur] + voff[dt][c]);
          o_acc[dt] = __builtin_amdgcn_mfma_f32_16x16x32_bf16(pa[c], bv, o_acc[dt], 0, 0, 0);
        }
      __builtin_amdgcn_s_setprio(0);

      __syncthreads();
      cur ^= 1;
    }

#pragma unroll
    for (int r = 0; r < 4; r++) {
      const int qg = q0w + g * 4 + r;
      const float inv = 1.0f / l_acc[r];
#pragma unroll
      for (int dt = 0; dt < 4; dt++)
        Out[(((size_t)b * S_ + qg) * H_ + h) * HD_ + dt * 16 + q] =
            f2bf(o_acc[dt][r] * inv);
    }
  };

  process(ip);
  process(31 - ip);
}

// ---------------- host launch ----------------
extern "C" void kernel_launch(void* const* d_in, const int* in_sizes, int n_in,
                              void* d_out, int out_size, void* d_ws, size_t ws_size,
                              hipStream_t stream) {
  const float* x  = (const float*)d_in[0];
  const float* rc = (const float*)d_in[1];
  const float* rs = (const float*)d_in[2];
  const float* Wq = (const float*)d_in[3];
  const float* Wk = (const float*)d_in[4];
  const float* Wv = (const float*)d_in[5];
  const float* Wo = (const float*)d_in[6];
  const float* qw = (const float*)d_in[7];
  const float* kw = (const float*)d_in[8];
  float* out = (float*)d_out;

  char* ws = (char*)d_ws;
  const size_t MB = (size_t)1 << 20;
  u16* xb   = (u16*)(ws + 0 * MB);    // 16 MB bf16 x (reused as attn-out)
  u16* wbq  = (u16*)(ws + 16 * MB);   // 12 MB bf16 [Wq;Wk;Wv]
  u16* wbo  = (u16*)(ws + 28 * MB);   // 8 MB  bf16 Wo
  u16* QKVb = (u16*)(ws + 36 * MB);   // 24 MB bf16 QKV proj (b,s,3072)
  u16* Vtb  = (u16*)(ws + 60 * MB);   // 4 MB  bf16 V (b,kvh,d,s) -> 64 MB
  u16* AO   = xb;

  const int MT = B_ * S_;
  const float QSC = 0.125f * 1.44269504089f;  // (1/sqrt(64)) * log2(e)

  // one fused convert pass: x, Wq, Wk, Wv, Wo -> bf16
  cvt_all<<<dim3(2048), 256, 0, stream>>>(x, Wq, Wk, Wv, Wo, xb, wbq, wbo);

  // QKV projection with fused RMSNorm+RoPE epilogue (Q scaled by log2e/8)
  gemm_qkv<<<dim3(NQK_ / BN, MT / BM), 256, 0, stream>>>(
      xb, wbq, QKVb, rc, rs, qw, kw, QSC, MT, NQK_, DM_);

  // V -> (b,kvh,d,s)
  v_transpose<<<dim3(S_ / 64, B_ * KVH_), 256, 0, stream>>>(QKVb, Vtb);

  // attention (R4 structure: 1024 balanced blocks, q-tile pairing)
  attn_fwd<<<dim3(16, 64), 256, 0, stream>>>(QKVb, Vtb, AO);

  // output projection -> d_out (fp32)
  gemm_bt<<<dim3(DM_ / BN, MT / BM), 256, 0, stream>>>(AO, wbo, out, MT, DM_, DM_);
}

// Round 11
// 203.220 us; speedup vs baseline: 1.2706x; 1.0172x over previous
//
#include <hip/hip_runtime.h>
#include <stdint.h>

#define B_ 2
#define S_ 2048
#define DM_ 2048
#define H_ 32
#define KVH_ 8
#define HD_ 64
#define NQK_ 3072   // 2048 q + 512 k + 512 v

typedef unsigned short u16;
typedef unsigned int u32;
typedef __attribute__((ext_vector_type(8))) short bf16x8;
typedef __attribute__((ext_vector_type(4))) float f32x4;

static __device__ __forceinline__ u16 f2bf(float f) {
  unsigned int u = __float_as_uint(f);
  u = (u + 0x7fffu + ((u >> 16) & 1u)) >> 16;
  return (u16)u;
}

// global -> LDS direct (width 16). LDS dest = wave-uniform base + lane*16.
static __device__ __forceinline__ void gload16(const void* g, void* lds_wave_base) {
  __builtin_amdgcn_global_load_lds(
      (__attribute__((address_space(1))) unsigned int*)(uintptr_t)g,
      (__attribute__((address_space(3))) unsigned int*)(uintptr_t)lds_wave_base,
      16, 0, 0);
}

// ---------------- fused fp32 -> bf16 convert (x, Wq, Wk, Wv, Wo) -----------
__global__ void cvt_all(const float* __restrict__ x, const float* __restrict__ wq,
                        const float* __restrict__ wk, const float* __restrict__ wv,
                        const float* __restrict__ wo,
                        u16* __restrict__ xb, u16* __restrict__ wbq,
                        u16* __restrict__ wbo) {
  const int NX = 2097152, NQ = 1048576, NKV = 262144;  // float4 counts
  const int TOT = NX + NQ + 2 * NKV + NQ;              // 4718592
  const int stride = gridDim.x * 256;
  for (int i = blockIdx.x * 256 + threadIdx.x; i < TOT; i += stride) {
    const float4* s; ushort4* d; int off;
    if (i < NX)                { s = (const float4*)x;  d = (ushort4*)xb;  off = i; }
    else if (i < NX + NQ)      { s = (const float4*)wq; d = (ushort4*)wbq; off = i - NX; }
    else if (i < NX + NQ + NKV){ s = (const float4*)wk; d = (ushort4*)(wbq + (size_t)DM_ * DM_); off = i - NX - NQ; }
    else if (i < NX + NQ + 2 * NKV) { s = (const float4*)wv; d = (ushort4*)(wbq + (size_t)DM_ * DM_ + (size_t)512 * DM_); off = i - NX - NQ - NKV; }
    else                       { s = (const float4*)wo; d = (ushort4*)wbo; off = i - NX - NQ - 2 * NKV; }
    const float4 v = s[off];
    ushort4 o;
    o.x = f2bf(v.x); o.y = f2bf(v.y); o.z = f2bf(v.z); o.w = f2bf(v.w);
    d[off] = o;
  }
}

// ---------------- GEMM: C(MxN) = A(MxK) * B(NxK)^T, bf16 in ----------------
// 2-phase double-buffered 128x128 (measured best structure).
#define BM 128
#define BN 128
#define BK 32

#define GEMM_MAIN                                                               \
  __shared__ u16 As[2][BM * BK];                                                \
  __shared__ u16 Bs[2][BN * BK];                                                \
  const int t = threadIdx.x;                                                    \
  const int lane = t & 63;                                                      \
  const int w = t >> 6;                                                         \
  const int q = lane & 15, g = lane >> 4;                                       \
  const int wr = (w >> 1) * 64, wc = (w & 1) * 64;                              \
  const int m0 = blockIdx.y * BM;                                               \
  const int n0 = blockIdx.x * BN;                                               \
  f32x4 acc[4][4] = {};                                                         \
  const char* Ab = (const char*)A;                                              \
  const char* Bb = (const char*)Bw;                                             \
  const size_t K2 = (size_t)K * 2;                                              \
  const int P0 = t * 16;                                                        \
  const int row0 = P0 >> 6, kb0 = P0 & 63;                                      \
  const int P1 = 4096 + t * 16;                                                 \
  const int row1 = P1 >> 6, kb1 = P1 & 63;                                      \
  const int Pb0 = (w << 10), Pb1 = 4096 + (w << 10);                            \
  auto STAGE = [&](int buf, int k0) {                                           \
    gload16(Ab + (size_t)(m0 + row0) * K2 + (size_t)k0 * 2 + kb0, (char*)As[buf] + Pb0); \
    gload16(Ab + (size_t)(m0 + row1) * K2 + (size_t)k0 * 2 + kb1, (char*)As[buf] + Pb1); \
    gload16(Bb + (size_t)(n0 + row0) * K2 + (size_t)k0 * 2 + kb0, (char*)Bs[buf] + Pb0); \
    gload16(Bb + (size_t)(n0 + row1) * K2 + (size_t)k0 * 2 + kb1, (char*)Bs[buf] + Pb1); \
  };                                                                            \
  STAGE(0, 0);                                                                  \
  __syncthreads();                                                              \
  int cur = 0;                                                                  \
  for (int k0 = 0; k0 < K; k0 += BK) {                                          \
    if (k0 + BK < K) STAGE(cur ^ 1, k0 + BK);                                   \
    bf16x8 af[4], bfr[4];                                                       \
    _Pragma("unroll")                                                           \
    for (int m = 0; m < 4; m++)                                                 \
      af[m] = *(const bf16x8*)((const char*)As[cur] +                           \
               (wr + m * 16 + q) * 64 + (g << 4));                              \
    _Pragma("unroll")                                                           \
    for (int n = 0; n < 4; n++)                                                 \
      bfr[n] = *(const bf16x8*)((const char*)Bs[cur] +                          \
               (wc + n * 16 + q) * 64 + (g << 4));                              \
    _Pragma("unroll")                                                           \
    for (int m = 0; m < 4; m++)                                                 \
      _Pragma("unroll")                                                         \
      for (int n = 0; n < 4; n++)                                               \
        acc[m][n] = __builtin_amdgcn_mfma_f32_16x16x32_bf16(af[m], bfr[n], acc[m][n], 0, 0, 0); \
    __syncthreads();                                                            \
    cur ^= 1;                                                                   \
  }

// fp32-out GEMM (O-projection)
__global__ __launch_bounds__(256) void gemm_bt(const u16* __restrict__ A,
                                               const u16* __restrict__ Bw,
                                               float* __restrict__ C,
                                               int M, int N, int K) {
  GEMM_MAIN
#pragma unroll
  for (int m = 0; m < 4; m++) {
    const int r0 = m0 + wr + m * 16 + g * 4;
#pragma unroll
    for (int n = 0; n < 4; n++) {
      const int c = n0 + wc + n * 16 + q;
#pragma unroll
      for (int j = 0; j < 4; j++)
        C[(size_t)(r0 + j) * N + c] = acc[m][n][j];
    }
  }
}

// QKV GEMM with fused RMSNorm + RoPE epilogue (bf16 out).
__global__ __launch_bounds__(256) void gemm_qkv(const u16* __restrict__ A,
                                                const u16* __restrict__ Bw,
                                                u16* __restrict__ C,
                                                const float* __restrict__ cosT,
                                                const float* __restrict__ sinT,
                                                const float* __restrict__ qwv,
                                                const float* __restrict__ kwv,
                                                float qscale,
                                                int M, int N, int K) {
  GEMM_MAIN
  const int hcol = (n0 + wc) >> 6;
  const bool isV = hcol >= 40;
  const bool isQ = hcol < 32;
  const float osc = isQ ? qscale : 1.0f;
  float wgt[4] = {1.f, 1.f, 1.f, 1.f};
  if (!isV) {
    const float* wp = isQ ? qwv : kwv;
#pragma unroll
    for (int n = 0; n < 4; n++) wgt[n] = wp[n * 16 + q];
  }
#pragma unroll
  for (int m = 0; m < 4; m++) {
#pragma unroll
    for (int j = 0; j < 4; j++) {
      const int row = m0 + wr + m * 16 + g * 4 + j;
      float v[4];
#pragma unroll
      for (int n = 0; n < 4; n++) v[n] = acc[m][n][j];
      if (!isV) {
        float ss = v[0] * v[0] + v[1] * v[1] + v[2] * v[2] + v[3] * v[3];
        ss += __shfl_xor(ss, 1, 64);
        ss += __shfl_xor(ss, 2, 64);
        ss += __shfl_xor(ss, 4, 64);
        ss += __shfl_xor(ss, 8, 64);
        const float inv = rsqrtf(ss * (1.0f / 64.0f) + 1e-6f);
        const int s = row & (S_ - 1);
        float xn[4];
#pragma unroll
        for (int n = 0; n < 4; n++) xn[n] = v[n] * inv * wgt[n];
#pragma unroll
        for (int n = 0; n < 4; n++) {
          const float rot = (n < 2) ? -xn[n + 2] : xn[n - 2];
          const int d = n * 16 + q;
          v[n] = (xn[n] * cosT[s * 64 + d] + rot * sinT[s * 64 + d]) * osc;
        }
      }
#pragma unroll
      for (int n = 0; n < 4; n++)
        C[(size_t)row * N + (n0 + wc + n * 16 + q)] = f2bf(v[n]);
    }
  }
}

// -------- V: bf16 QKV v-part (b,s,kvh,d) -> bf16 (b,kvh,d,s) ---------------
__global__ void v_transpose(const u16* __restrict__ QKV, u16* __restrict__ Vt) {
  __shared__ u16 tile[64][72];
  const int s0 = blockIdx.x * 64;
  const int bk = blockIdx.y;
  const int b = bk / KVH_, kvh = bk % KVH_;
  const int t = threadIdx.x;
#pragma unroll
  for (int it = 0; it < 16; it++) {
    int idx = it * 256 + t;
    int sl = idx >> 6, d = idx & 63;
    tile[sl][d] = QKV[(size_t)(b * S_ + s0 + sl) * NQK_ + 2560 + kvh * 64 + d];
  }
  __syncthreads();
#pragma unroll
  for (int it = 0; it < 16; it++) {
    int idx = it * 256 + t;
    int d = idx >> 6, sl = idx & 63;
    Vt[(((size_t)(b * KVH_ + kvh)) * HD_ + d) * S_ + s0 + sl] = tile[sl][d];
  }
}

// ---------------- flash attention (merged paired-tile kt loop) --------------
// Constant-shift softmax (P = exp2(s-12), shift folded into MFMA C-init).
// Low tile (qt=ip) and high tile (qt=31-ip) share ONE kt loop: low active
// while kt<=ip (block-uniform), high always. One barrier + one staging per kt
// instead of two loops (33 -> 32-ip iterations per block).
__global__ __launch_bounds__(256, 4) void attn_fwd(const u16* __restrict__ QKV,
                                                   const u16* __restrict__ Vt,
                                                   u16* __restrict__ Out) {
  __shared__ u16 Ksm[2][64 * 64];   // [key][d], XOR-swizzled 128B rows
  __shared__ u16 Vsm[2][64 * 64];   // [d][key], XOR-swizzled 128B rows
  __shared__ u16 Psm[4][16 * 64];   // per-wave P tile [q][kk], swizzled

  const int t = threadIdx.x, lane = t & 63, w = t >> 6;
  const int q = lane & 15, g = lane >> 4;

  const int fid = blockIdx.y * 16 + blockIdx.x;   // 0..1023
  const int xcd = fid & 7, slot = fid >> 3;       // slot 0..127
  const int kg = xcd * 2 + (slot >> 6);           // (b,kvh) group 0..15
  const int sub = slot & 63;
  const int ip = sub >> 2;                        // q-tile pair index 0..15
  const int b = kg >> 3, kvh = kg & 7;
  const int h = kvh * 4 + (sub & 3);

  const char* Kb = (const char*)(QKV + (size_t)b * S_ * NQK_ + 2048 + kvh * 64);
  const char* Vb = (const char*)(Vt + ((size_t)(b * KVH_ + kvh)) * HD_ * S_);

  const int SP0 = t * 16, SP1 = 4096 + t * 16;
  const int srow0 = SP0 >> 7, scb0 = (SP0 ^ ((srow0 & 7) << 4)) & 127;
  const int srow1 = SP1 >> 7, scb1 = (SP1 ^ ((srow1 & 7) << 4)) & 127;
  const int SB0 = (w << 10), SB1 = 4096 + (w << 10);
  const size_t KROW = (size_t)NQK_ * 2;

  auto STAGE = [&](int buf, int kt) {
    gload16(Kb + (size_t)(kt * 64 + srow0) * KROW + scb0, (char*)Ksm[buf] + SB0);
    gload16(Kb + (size_t)(kt * 64 + srow1) * KROW + scb1, (char*)Ksm[buf] + SB1);
    gload16(Vb + (size_t)srow0 * (S_ * 2) + (size_t)kt * 128 + scb0, (char*)Vsm[buf] + SB0);
    gload16(Vb + (size_t)srow1 * (S_ * 2) + (size_t)kt * 128 + scb1, (char*)Vsm[buf] + SB1);
  };

  const int swz = (q & 7) << 4;
  int koff[4][2], pwoff[4][2], proff[2];
#pragma unroll
  for (int nt = 0; nt < 4; nt++)
#pragma unroll
    for (int hh = 0; hh < 2; hh++) {
      koff[nt][hh] = ((nt * 16 + q) * 128 + hh * 64 + g * 16) ^ swz;
      pwoff[nt][hh] = (q * 128 + nt * 32 + g * 8 + hh * 4) ^ swz;
    }
#pragma unroll
  for (int c = 0; c < 2; c++) proff[c] = (q * 128 + c * 64 + g * 16) ^ swz;

  bf16x8 ones;
#pragma unroll
  for (int j = 0; j < 8; j++) ones[j] = (short)0x3F80;

  const int qlo = ip, qhi = 31 - ip;

  // Q fragments for both tiles
  bf16x8 aqL[2], aqH[2];
  {
    const u16* qpL = QKV + (size_t)(b * S_ + qlo * 64 + w * 16 + q) * NQK_ + h * 64 + g * 8;
    const u16* qpH = QKV + (size_t)(b * S_ + qhi * 64 + w * 16 + q) * NQK_ + h * 64 + g * 8;
    aqL[0] = *(const bf16x8*)qpL;
    aqL[1] = *(const bf16x8*)(qpL + 32);
    aqH[0] = *(const bf16x8*)qpH;
    aqH[1] = *(const bf16x8*)(qpH + 32);
  }

  f32x4 oL[4] = {}, oH[4] = {};
  f32x4 lL = {}, lH = {};

  int cur = 0;

  // one tile's full per-kt phase (QK -> mask -> exp2 -> P-LDS -> l,PV)
  auto tile_step = [&](int kt, int qt, const bf16x8* aq, f32x4* o_acc, f32x4& l_acc) {
    f32x4 sc[4];
    __builtin_amdgcn_s_setprio(1);
#pragma unroll
    for (int nt = 0; nt < 4; nt++) {
      f32x4 s = {-12.0f, -12.0f, -12.0f, -12.0f};  // softmax shift folded in
#pragma unroll
      for (int hh = 0; hh < 2; hh++) {
        bf16x8 bk = *(const bf16x8*)((const char*)Ksm[cur] + koff[nt][hh]);
        s = __builtin_amdgcn_mfma_f32_16x16x32_bf16(bk, aq[hh], s, 0, 0, 0);
      }
      sc[nt] = s;
    }
    __builtin_amdgcn_s_setprio(0);

    if (kt == qt) {  // diagonal-tile causal mask
#pragma unroll
      for (int nt = 0; nt < 4; nt++)
#pragma unroll
        for (int r = 0; r < 4; r++)
          if (nt * 16 + g * 4 + r > w * 16 + q) sc[nt][r] = -1e30f;
    }

    // P = exp2(s) in (0,1] (scores pre-shifted by -12; bound |s|<=11.6)
#pragma unroll
    for (int nt = 0; nt < 4; nt++)
#pragma unroll
      for (int r = 0; r < 4; r++) sc[nt][r] = exp2f(sc[nt][r]);
#pragma unroll
    for (int nt = 0; nt < 4; nt++)
#pragma unroll
      for (int hh = 0; hh < 2; hh++) {
        u32 wv;
        asm("v_cvt_pk_bf16_f32 %0, %1, %2"
            : "=v"(wv) : "v"(sc[nt][2 * hh]), "v"(sc[nt][2 * hh + 1]));
        *(u32*)((char*)Psm[w] + pwoff[nt][hh]) = wv;
      }

    asm volatile("s_waitcnt lgkmcnt(0)" ::: "memory");
    __builtin_amdgcn_sched_barrier(0);

    bf16x8 pa[2];
#pragma unroll
    for (int c = 0; c < 2; c++)
      pa[c] = *(const bf16x8*)((const char*)Psm[w] + proff[c]);

    __builtin_amdgcn_s_setprio(1);
    l_acc = __builtin_amdgcn_mfma_f32_16x16x32_bf16(pa[0], ones, l_acc, 0, 0, 0);
    l_acc = __builtin_amdgcn_mfma_f32_16x16x32_bf16(pa[1], ones, l_acc, 0, 0, 0);
#pragma unroll
    for (int c = 0; c < 2; c++)
#pragma unroll
      for (int dt = 0; dt < 4; dt++) {
        bf16x8 bv = *(const bf16x8*)((const char*)Vsm[cur] + koff[dt][c]);
        o_acc[dt] = __builtin_amdgcn_mfma_f32_16x16x32_bf16(pa[c], bv, o_acc[dt], 0, 0, 0);
      }
    __builtin_amdgcn_s_setprio(0);
  };

  STAGE(0, 0);
  __syncthreads();

  for (int kt = 0; kt <= qhi; kt++) {
    if (kt < qhi) STAGE(cur ^ 1, kt + 1);
    if (kt <= qlo) tile_step(kt, qlo, aqL, oL, lL);   // block-uniform branch
    tile_step(kt, qhi, aqH, oH, lH);
    __syncthreads();
    cur ^= 1;
  }

  // epilogues: O /= l, write bf16 (b,s,h,d)
  auto write_out = [&](int qt, const f32x4* o_acc, const f32x4& l_acc) {
#pragma unroll
    for (int r = 0; r < 4; r++) {
      const int qg = qt * 64 + w * 16 + g * 4 + r;
      const float inv = 1.0f / l_acc[r];
#pragma unroll
      for (int dt = 0; dt < 4; dt++)
        Out[(((size_t)b * S_ + qg) * H_ + h) * HD_ + dt * 16 + q] =
            f2bf(o_acc[dt][r] * inv);
    }
  };
  write_out(qlo, oL, lL);
  write_out(qhi, oH, lH);
}

// ---------------- host launch ----------------
extern "C" void kernel_launch(void* const* d_in, const int* in_sizes, int n_in,
                              void* d_out, int out_size, void* d_ws, size_t ws_size,
                              hipStream_t stream) {
  const float* x  = (const float*)d_in[0];
  const float* rc = (const float*)d_in[1];
  const float* rs = (const float*)d_in[2];
  const float* Wq = (const float*)d_in[3];
  const float* Wk = (const float*)d_in[4];
  const float* Wv = (const float*)d_in[5];
  const float* Wo = (const float*)d_in[6];
  const float* qw = (const float*)d_in[7];
  const float* kw = (const float*)d_in[8];
  float* out = (float*)d_out;

  char* ws = (char*)d_ws;
  const size_t MB = (size_t)1 << 20;
  u16* xb   = (u16*)(ws + 0 * MB);    // 16 MB bf16 x (reused as attn-out)
  u16* wbq  = (u16*)(ws + 16 * MB);   // 12 MB bf16 [Wq;Wk;Wv]
  u16* wbo  = (u16*)(ws + 28 * MB);   // 8 MB  bf16 Wo
  u16* QKVb = (u16*)(ws + 36 * MB);   // 24 MB bf16 QKV proj (b,s,3072)
  u16* Vtb  = (u16*)(ws + 60 * MB);   // 4 MB  bf16 V (b,kvh,d,s) -> 64 MB
  u16* AO   = xb;

  const int MT = B_ * S_;
  const float QSC = 0.125f * 1.44269504089f;  // (1/sqrt(64)) * log2(e)

  // one fused convert pass: x, Wq, Wk, Wv, Wo -> bf16
  cvt_all<<<dim3(2048), 256, 0, stream>>>(x, Wq, Wk, Wv, Wo, xb, wbq, wbo);

  // QKV projection with fused RMSNorm+RoPE epilogue (Q scaled by log2e/8)
  gemm_qkv<<<dim3(NQK_ / BN, MT / BM), 256, 0, stream>>>(
      xb, wbq, QKVb, rc, rs, qw, kw, QSC, MT, NQK_, DM_);

  // V -> (b,kvh,d,s)
  v_transpose<<<dim3(S_ / 64, B_ * KVH_), 256, 0, stream>>>(QKVb, Vtb);

  // attention (merged paired-tile loop, 1024 balanced blocks)
  attn_fwd<<<dim3(16, 64), 256, 0, stream>>>(QKVb, Vtb, AO);

  // output projection -> d_out (fp32)
  gemm_bt<<<dim3(DM_ / BN, MT / BM), 256, 0, stream>>>(AO, wbo, out, MT, DM_, DM_);
}